// Round 13
// baseline (1103.985 us; speedup 1.0000x reference)
//
#include <hip/hip_runtime.h>

// Flash-attention forward, causal, B=4 H=16 S=2048 D=128, fp32 in/out.
// Round 13: merge the V-transpose prepass INTO the main kernel (doorbell
// overlap). ws layout: [0..1023] control ints (cnt_attn, tchk[64], done[64],
// zeroed by hipMemsetAsync), then Vt bf16 [bh][d][s].
//   Each WG pops an attention item (LPT), then ENSURES its bh's V^T is ready:
//   helps transpose that bh's 64 chunks (64s x 64d each) via per-bh atomic
//   chunk counter, then spins on done[bh]==64 (device-scope doorbell:
//   writers __threadfence + atomicAdd; readers atomic-load + __threadfence).
//   Transpose BW-work thus overlaps attention compute instead of serializing.
//   Attention body = R9 verbatim: 8 waves, 32x32 MFMA swapped QK^T, K fp32
//   reg-staged->bf16 in-kernel, V via global_load_lds (pre-swizzled source),
//   in-reg exp2 softmax, defer-max, cvt_pk+permlane32_swap, 2-buf LDS.

#define SLEN 2048
#define DDIM 128
#define NBH  64
#define QB   256
#define KB   64
#define NITEMS 512

typedef __bf16 bf16x8 __attribute__((ext_vector_type(8)));
typedef float  f32x16 __attribute__((ext_vector_type(16)));
typedef float  f32x4  __attribute__((ext_vector_type(4)));
typedef unsigned uint32x4 __attribute__((ext_vector_type(4)));
typedef unsigned short ushort_t;
typedef ushort_t ushort8 __attribute__((ext_vector_type(8)));

__device__ inline ushort_t f2bf(float f) {
  union { float f; unsigned u; } v; v.f = f;
  unsigned u = v.u;
  u += 0x7FFFu + ((u >> 16) & 1u);   // RNE, finite inputs only
  return (ushort_t)(u >> 16);
}

__device__ inline unsigned cvtpk_bf16(float lo, float hi) {
  unsigned r;
  asm("v_cvt_pk_bf16_f32 %0, %1, %2" : "=v"(r) : "v"(lo), "v"(hi));
  return r;
}

__device__ inline float exp2_fast(float x) {
  float r;
  asm("v_exp_f32 %0, %1" : "=v"(r) : "v"(x));
  return r;
}

// ---------------- merged kernel: transpose-help + persistent attention ------
__global__ __launch_bounds__(512, 1) void fattn13_kernel(
    const float* __restrict__ Q, const float* __restrict__ Kf32,
    const float* __restrict__ Vf32, ushort_t* __restrict__ Vt,
    float* __restrict__ Out, int* __restrict__ ctrl) {
  __shared__ ushort_t K_sh[2][KB * DDIM];   // [buf][k][d]  16KB each
  __shared__ ushort_t V_sh[2][DDIM * KB];   // [buf][d][k]  16KB each
  __shared__ float    tbuf[64][65];         // transpose staging (16.25KB)
  __shared__ int item_sh;
  __shared__ int ctrl_sh;

  int* cnt_attn = ctrl;        // [0]
  int* tchk     = ctrl + 1;    // [1..64]  per-bh transpose chunk counter
  int* done     = ctrl + 65;   // [65..128] per-bh completed-chunk counter

  const int tid  = threadIdx.x;
  const int lane = tid & 63;
  const int wv   = tid >> 6;         // 0..7
  const int l31  = lane & 31;
  const int hi   = lane >> 5;        // 0/1

  // 1/sqrt(128) * log2(e): softmax runs in exp2 domain
  const float qscale = 0.12751744f;
  const float THR = 11.0f;           // defer-max threshold (log2 units)

  // K staging registers (2 chunks of 8 floats each), static-indexed
  float4 kr0a, kr0b, kr1a, kr1b;
  const int kch0 = tid;              // chunk ids: j*512 + tid
  const int kch1 = 512 + tid;
  const int krow0 = kch0 >> 4, kp0 = kch0 & 15;
  const int krow1 = kch1 >> 4, kp1 = kch1 & 15;
  const int kgc0 = kp0 ^ (krow0 & 7);          // global chunk (pre-swizzle)
  const int kgc1 = kp1 ^ (krow1 & 7);

  while (true) {
    if (tid == 0) item_sh = atomicAdd(cnt_attn, 1);
    __syncthreads();
    const int item = item_sh;
    if (item >= NITEMS) break;

    const int qblk = 7 - (item >> 6);   // heavy-first (LPT)
    const int bh   = item & 63;

    // ======== ensure V^T[bh] ready: help-transpose then doorbell ========
    while (true) {
      if (tid == 0) {
        int d = __hip_atomic_load(done + bh, __ATOMIC_RELAXED,
                                  __HIP_MEMORY_SCOPE_AGENT);
        ctrl_sh = (d >= 64) ? -1 : atomicAdd(tchk + bh, 1);
      }
      __syncthreads();
      const int c = ctrl_sh;
      __syncthreads();
      if (c == -1) break;               // bh fully transposed + visible
      if (c < 64) {
        // ---- chunk c of bh: 64 s-rows x 64 d-cols ----
        const int s0 = (c >> 1) * 64;
        const int d0 = (c & 1) * 64;
        const float* src = Vf32 + ((size_t)bh * SLEN + s0) * DDIM + d0;
        const int tx = tid & 63;        // d
        const int ty = tid >> 6;        // s base 0..7
#pragma unroll
        for (int j = 0; j < 8; ++j) {
          int s = ty + j * 8;
          tbuf[s][tx] = src[(size_t)s * DDIM + tx];
        }
        __syncthreads();
        const int sl2 = (tid & 31) * 2;  // s pair
        const int dl  = tid >> 5;        // 0..15
        ushort_t* dst = Vt + ((size_t)bh * DDIM + d0) * SLEN + s0;
#pragma unroll
        for (int j = 0; j < 4; ++j) {
          int d = dl + j * 16;
          unsigned lo = f2bf(tbuf[sl2][d]);
          unsigned hh = f2bf(tbuf[sl2 + 1][d]);
          *reinterpret_cast<unsigned*>(&dst[(size_t)d * SLEN + sl2]) =
              lo | (hh << 16);
        }
        __threadfence();                // make stores device-visible
        __syncthreads();
        if (tid == 0) atomicAdd(done + bh, 1);
      }
      // c >= 64: all chunks claimed; loop re-checks done (poppers finishing)
    }
    __threadfence();                    // acquire side of the doorbell
    __syncthreads();

    // ======== attention body (R9 verbatim) ========
    const float*    Qp = Q    + (size_t)bh * SLEN * DDIM;
    const float*    Kp = Kf32 + (size_t)bh * SLEN * DDIM;
    const ushort_t* Vp = Vt   + (size_t)bh * DDIM * SLEN;
    float*          Op = Out  + (size_t)bh * SLEN * DDIM;

    const int q0w = qblk * QB + wv * 32;   // wave's first q row
    const int qg  = q0w + l31;             // this lane's q row

    // ---- Q fragments: B-operand of S^T = K·Q^T ----
    bf16x8 qf[8];
    {
      const float* qr = Qp + (size_t)qg * DDIM;
#pragma unroll
      for (int ds = 0; ds < 8; ++ds) {
        int d0 = ds * 16 + hi * 8;
        float4 x = *reinterpret_cast<const float4*>(qr + d0);
        float4 y = *reinterpret_cast<const float4*>(qr + d0 + 4);
        ushort8 uu;
        uu[0] = f2bf(x.x * qscale); uu[1] = f2bf(x.y * qscale);
        uu[2] = f2bf(x.z * qscale); uu[3] = f2bf(x.w * qscale);
        uu[4] = f2bf(y.x * qscale); uu[5] = f2bf(y.y * qscale);
        uu[6] = f2bf(y.z * qscale); uu[7] = f2bf(y.w * qscale);
        qf[ds] = __builtin_bit_cast(bf16x8, uu);
      }
    }

    f32x16 Oacc[4];
#pragma unroll
    for (int dt = 0; dt < 4; ++dt)
#pragma unroll
      for (int r = 0; r < 16; ++r) Oacc[dt][r] = 0.f;
    float m_run = -3.0e38f, l_run = 0.f;

    const int last_kb       = qblk * 4 + 3;
    const int last_kb_wave  = (q0w + 31) >> 6;

    // ---- K load (fp32 -> regs), pre-swizzled source ----
    auto kload = [&](int kb) {
      const float* ksrc = Kp + (size_t)kb * KB * DDIM;
      const float* g0 = ksrc + krow0 * DDIM + kgc0 * 8;
      const float* g1 = ksrc + krow1 * DDIM + kgc1 * 8;
      kr0a = *reinterpret_cast<const float4*>(g0);
      kr0b = *reinterpret_cast<const float4*>(g0 + 4);
      kr1a = *reinterpret_cast<const float4*>(g1);
      kr1b = *reinterpret_cast<const float4*>(g1 + 4);
    };
    // ---- K write (cvt_pk + ds_write_b128 to linear position) ----
    auto kwrite = [&](int buf) {
      uint32x4 w0, w1;
      w0.x = cvtpk_bf16(kr0a.x, kr0a.y); w0.y = cvtpk_bf16(kr0a.z, kr0a.w);
      w0.z = cvtpk_bf16(kr0b.x, kr0b.y); w0.w = cvtpk_bf16(kr0b.z, kr0b.w);
      w1.x = cvtpk_bf16(kr1a.x, kr1a.y); w1.y = cvtpk_bf16(kr1a.z, kr1a.w);
      w1.z = cvtpk_bf16(kr1b.x, kr1b.y); w1.w = cvtpk_bf16(kr1b.z, kr1b.w);
      *reinterpret_cast<uint32x4*>(&K_sh[buf][krow0 * DDIM + kp0 * 8]) = w0;
      *reinterpret_cast<uint32x4*>(&K_sh[buf][krow1 * DDIM + kp1 * 8]) = w1;
    };
    // ---- V stage via global_load_lds (bf16, pre-swizzled source) ----
    auto vstage = [&](int buf, int kb) {
      const ushort_t* vsrc = Vp + (size_t)kb * KB;
#pragma unroll
      for (int j = 0; j < 2; ++j) {
        int chunk = wv * 128 + j * 64 + lane;
        int row = chunk >> 3, c = chunk & 7;
        const ushort_t* g = vsrc + (size_t)row * SLEN + ((c ^ (row & 7)) << 3);
        ushort_t* l = &V_sh[buf][(wv * 128 + j * 64) * 8];
        __builtin_amdgcn_global_load_lds(
            (const __attribute__((address_space(1))) unsigned*)g,
            (__attribute__((address_space(3))) unsigned*)l, 16, 0, 0);
      }
    };

    // ---- prologue: stage tile 0 ----
    kload(0);
    vstage(0, 0);
    kwrite(0);
    __syncthreads();

    for (int kb = 0; kb <= last_kb; ++kb) {
      const int buf = kb & 1;
      if (kb < last_kb) {              // issue next tile's loads early (T14)
        kload(kb + 1);
        vstage(buf ^ 1, kb + 1);
      }

      if (kb <= last_kb_wave) {
        // ---- S^T = K·Q^T ----
        f32x16 sac[2];
#pragma unroll
        for (int mt = 0; mt < 2; ++mt) {
          f32x16 a;
#pragma unroll
          for (int r = 0; r < 16; ++r) a[r] = 0.f;
          int row = mt * 32 + l31;
          int sw = row & 7;
          __builtin_amdgcn_s_setprio(1);
#pragma unroll
          for (int ds = 0; ds < 8; ++ds) {
            int c = ds * 2 + hi;
            bf16x8 kf = *reinterpret_cast<const bf16x8*>(
                &K_sh[buf][row * DDIM + ((c ^ sw) << 3)]);
            a = __builtin_amdgcn_mfma_f32_32x32x16_bf16(kf, qf[ds], a, 0, 0, 0);
          }
          __builtin_amdgcn_s_setprio(0);
          sac[mt] = a;
        }

        // ---- causal mask (diagonal-crossing tiles only) ----
        if (kb * 64 + 63 > q0w) {
#pragma unroll
          for (int mt = 0; mt < 2; ++mt) {
            int kbase = kb * 64 + mt * 32 + 4 * hi;
#pragma unroll
            for (int r = 0; r < 16; ++r) {
              int krow = (r & 3) + 8 * (r >> 2);
              if (kbase + krow > qg) sac[mt][r] = -3.0e38f;
            }
          }
        }

        // ---- tile max: 4-way partial chains ----
        float p0 = sac[0][0], p1 = sac[0][1], p2 = sac[0][2], p3 = sac[0][3];
#pragma unroll
        for (int r = 4; r < 16; r += 4) {
          p0 = fmaxf(p0, sac[0][r + 0]); p1 = fmaxf(p1, sac[0][r + 1]);
          p2 = fmaxf(p2, sac[0][r + 2]); p3 = fmaxf(p3, sac[0][r + 3]);
        }
#pragma unroll
        for (int r = 0; r < 16; r += 4) {
          p0 = fmaxf(p0, sac[1][r + 0]); p1 = fmaxf(p1, sac[1][r + 1]);
          p2 = fmaxf(p2, sac[1][r + 2]); p3 = fmaxf(p3, sac[1][r + 3]);
        }
        float tm = fmaxf(fmaxf(p0, p1), fmaxf(p2, p3));
        tm = fmaxf(tm, __shfl_xor(tm, 32));

        // ---- defer-max ----
        if (!__all(tm - m_run <= THR)) {
          float mnew  = fmaxf(m_run, tm);
          float alpha = exp2_fast(m_run - mnew);
          m_run = mnew;
          l_run *= alpha;
#pragma unroll
          for (int dt = 0; dt < 4; ++dt)
#pragma unroll
            for (int r = 0; r < 16; ++r) Oacc[dt][r] *= alpha;
        }

        // ---- P = exp2(S - m), 4-way partial sums ----
        float s0 = 0.f, s1 = 0.f, s2 = 0.f, s3 = 0.f;
#pragma unroll
        for (int mt = 0; mt < 2; ++mt)
#pragma unroll
          for (int r = 0; r < 16; r += 4) {
            float e0 = exp2_fast(sac[mt][r + 0] - m_run);
            float e1 = exp2_fast(sac[mt][r + 1] - m_run);
            float e2 = exp2_fast(sac[mt][r + 2] - m_run);
            float e3 = exp2_fast(sac[mt][r + 3] - m_run);
            sac[mt][r + 0] = e0; sac[mt][r + 1] = e1;
            sac[mt][r + 2] = e2; sac[mt][r + 3] = e3;
            s0 += e0; s1 += e1; s2 += e2; s3 += e3;
          }
        float rs = (s0 + s1) + (s2 + s3);
        rs += __shfl_xor(rs, 32);
        l_run += rs;

        // ---- P^T fragments: cvt_pk + permlane32_swap ----
        uint32x4 pw[4];
#pragma unroll
        for (int ks = 0; ks < 4; ++ks) {
          const int mt = ks >> 1;
          const int hb = 8 * (ks & 1);
          unsigned X  = cvtpk_bf16(sac[mt][hb + 0], sac[mt][hb + 1]);
          unsigned X2 = cvtpk_bf16(sac[mt][hb + 2], sac[mt][hb + 3]);
          unsigned Y  = cvtpk_bf16(sac[mt][hb + 4], sac[mt][hb + 5]);
          unsigned Y2 = cvtpk_bf16(sac[mt][hb + 6], sac[mt][hb + 7]);
          asm("v_permlane32_swap_b32 %0, %1" : "+v"(X),  "+v"(Y));
          asm("v_permlane32_swap_b32 %0, %1" : "+v"(X2), "+v"(Y2));
          uint32x4 f; f.x = X; f.y = X2; f.z = Y; f.w = Y2;
          pw[ks] = f;
        }

        // ---- O^T += V^T · P^T ----
#pragma unroll
        for (int dt = 0; dt < 4; ++dt) {
          int row = dt * 32 + l31;
          int sw = row & 7;
          __builtin_amdgcn_s_setprio(1);
#pragma unroll
          for (int ks = 0; ks < 4; ++ks) {
            int c = ks * 2 + hi;
            bf16x8 vf = *reinterpret_cast<const bf16x8*>(
                &V_sh[buf][row * 64 + ((c ^ sw) << 3)]);
            Oacc[dt] = __builtin_amdgcn_mfma_f32_32x32x16_bf16(
                vf, __builtin_bit_cast(bf16x8, pw[ks]), Oacc[dt], 0, 0, 0);
          }
          __builtin_amdgcn_s_setprio(0);
        }
      }

      if (kb < last_kb) kwrite(buf ^ 1);   // convert+publish next K tile
      __syncthreads();                     // tile kb+1 resident for all waves
    }

    // ---- epilogue: O[q][d] = O^T normalized, float4 stores ----
    {
      float invl = 1.0f / l_run;
      float* orow = Op + (size_t)qg * DDIM;
#pragma unroll
      for (int dt = 0; dt < 4; ++dt)
#pragma unroll
        for (int rq = 0; rq < 4; ++rq) {
          float4 o;
          o.x = Oacc[dt][rq * 4 + 0] * invl;
          o.y = Oacc[dt][rq * 4 + 1] * invl;
          o.z = Oacc[dt][rq * 4 + 2] * invl;
          o.w = Oacc[dt][rq * 4 + 3] * invl;
          int d = dt * 32 + 8 * rq + 4 * hi;
          *reinterpret_cast<float4*>(orow + d) = o;
        }
    }
    __syncthreads();   // protect item_sh + LDS reuse across items
  }
}

// ---------------- fallback (fp32-direct kernel, used if ws too small) --------
__global__ __launch_bounds__(256) void fattn_kernel(
    const float* __restrict__ Q, const float* __restrict__ K,
    const float* __restrict__ V, float* __restrict__ Out) {
  __shared__ ushort_t Kf_sh[64 * 128];
  __shared__ ushort_t Vf_sh[128 * 64];
  __shared__ ushort_t P_sh[4][16 * 64];

  const int tid  = threadIdx.x;
  const int lane = tid & 63;
  const int wv   = tid >> 6;
  const int l16  = lane & 15;
  const int lhi  = lane >> 4;
  const int qblk = blockIdx.x;
  const int bh   = blockIdx.y;
  const float scale = 0.08838834764831845f;

  const size_t base = (size_t)bh * SLEN * DDIM;
  const float* Qp = Q + base;
  const float* Kp = K + base;
  const float* Vp = V + base;
  float*       Op = Out + base;

  bf16x8 qf[4];
  {
    const int qrow = qblk * 64 + wv * 16 + l16;
    const float* qr = Qp + (size_t)qrow * DDIM;
#pragma unroll
    for (int dc = 0; dc < 4; ++dc) {
      int d0 = dc * 32 + lhi * 8;
      float4 x = *reinterpret_cast<const float4*>(qr + d0);
      float4 y = *reinterpret_cast<const float4*>(qr + d0 + 4);
      ushort8 uu;
      uu[0] = f2bf(x.x * scale); uu[1] = f2bf(x.y * scale);
      uu[2] = f2bf(x.z * scale); uu[3] = f2bf(x.w * scale);
      uu[4] = f2bf(y.x * scale); uu[5] = f2bf(y.y * scale);
      uu[6] = f2bf(y.z * scale); uu[7] = f2bf(y.w * scale);
      qf[dc] = __builtin_bit_cast(bf16x8, uu);
    }
  }

  f32x4 Oacc[8];
#pragma unroll
  for (int i = 0; i < 8; ++i) Oacc[i] = (f32x4){0.f, 0.f, 0.f, 0.f};
  float m_run[4], l_run[4];
#pragma unroll
  for (int r = 0; r < 4; ++r) { m_run[r] = -3.0e38f; l_run[r] = 0.f; }

  for (int kb = 0; kb <= qblk; ++kb) {
    __syncthreads();
    {
      const float* src = Kp + (size_t)kb * 64 * DDIM;
#pragma unroll
      for (int it = 0; it < 8; ++it) {
        int idx4 = it * 256 + tid;
        int r  = idx4 >> 5;
        int c4 = idx4 & 31;
        float4 x = *reinterpret_cast<const float4*>(src + r * DDIM + c4 * 4);
        unsigned lo = ((unsigned)f2bf(x.y) << 16) | f2bf(x.x);
        unsigned hh = ((unsigned)f2bf(x.w) << 16) | f2bf(x.z);
        int e = (r * 128 + c4 * 4) ^ ((r & 7) << 3);
        *reinterpret_cast<uint2*>(&Kf_sh[e]) = make_uint2(lo, hh);
      }
      const float* vs = Vp + (size_t)kb * 64 * DDIM;
#pragma unroll
      for (int it = 0; it < 8; ++it) {
        int idx4 = it * 256 + tid;
        int r  = idx4 >> 5;
        int c4 = idx4 & 31;
        float4 x = *reinterpret_cast<const float4*>(vs + r * DDIM + c4 * 4);
        int c0 = c4 * 4;
        float vals[4] = {x.x, x.y, x.z, x.w};
#pragma unroll
        for (int j = 0; j < 4; ++j) {
          int d = c0 + j;
          Vf_sh[(d * 64 + r) ^ ((d & 7) << 3)] = f2bf(vals[j]);
        }
      }
    }
    __syncthreads();

    f32x4 sacc[4];
#pragma unroll
    for (int g = 0; g < 4; ++g) {
      f32x4 acc = (f32x4){0.f, 0.f, 0.f, 0.f};
#pragma unroll
      for (int dc = 0; dc < 4; ++dc) {
        int row = g * 16 + l16;
        int e = (row * 128 + dc * 32 + lhi * 8) ^ ((row & 7) << 3);
        bf16x8 kf = *reinterpret_cast<const bf16x8*>(&Kf_sh[e]);
        acc = __builtin_amdgcn_mfma_f32_16x16x32_bf16(qf[dc], kf, acc, 0, 0, 0);
      }
      sacc[g] = acc;
    }

    if (kb == qblk) {
      int q0 = lhi * 4;
#pragma unroll
      for (int g = 0; g < 4; ++g) {
        int kcol = g * 16 + l16;
#pragma unroll
        for (int r = 0; r < 4; ++r) {
          if (kcol > wv * 16 + q0 + r) sacc[g][r] = -3.0e38f;
        }
      }
    }

    float tmax[4];
#pragma unroll
    for (int r = 0; r < 4; ++r)
      tmax[r] = fmaxf(fmaxf(sacc[0][r], sacc[1][r]),
                      fmaxf(sacc[2][r], sacc[3][r]));
#pragma unroll
    for (int x = 1; x < 16; x <<= 1) {
#pragma unroll
      for (int r = 0; r < 4; ++r)
        tmax[r] = fmaxf(tmax[r], __shfl_xor(tmax[r], x));
    }

    float alpha[4], mnew[4];
#pragma unroll
    for (int r = 0; r < 4; ++r) {
      mnew[r]  = fmaxf(m_run[r], tmax[r]);
      alpha[r] = __expf(m_run[r] - mnew[r]);
      m_run[r] = mnew[r];
    }

    float rsum[4] = {0.f, 0.f, 0.f, 0.f};
#pragma unroll
    for (int g = 0; g < 4; ++g) {
#pragma unroll
      for (int r = 0; r < 4; ++r) {
        float p = __expf(sacc[g][r] - mnew[r]);
        rsum[r] += p;
        int prow = lhi * 4 + r;
        P_sh[wv][(prow * 64 + g * 16 + l16) ^ ((prow & 7) << 3)] = f2bf(p);
      }
    }
#pragma unroll
    for (int x = 1; x < 16; x <<= 1) {
#pragma unroll
      for (int r = 0; r < 4; ++r) rsum[r] += __shfl_xor(rsum[r], x);
    }
#pragma unroll
    for (int r = 0; r < 4; ++r) l_run[r] = l_run[r] * alpha[r] + rsum[r];

#pragma unroll
    for (int dg = 0; dg < 8; ++dg)
#pragma unroll
      for (int r = 0; r < 4; ++r) Oacc[dg][r] *= alpha[r];

    bf16x8 pf[2];
#pragma unroll
    for (int kc = 0; kc < 2; ++kc) {
      int e = (l16 * 64 + kc * 32 + lhi * 8) ^ ((l16 & 7) << 3);
      pf[kc] = *reinterpret_cast<const bf16x8*>(&P_sh[wv][e]);
    }
#pragma unroll
    for (int dg = 0; dg < 8; ++dg) {
#pragma unroll
      for (int kc = 0; kc < 2; ++kc) {
        int row = dg * 16 + l16;
        int e = (row * 64 + kc * 32 + lhi * 8) ^ ((row & 7) << 3);
        bf16x8 vf = *reinterpret_cast<const bf16x8*>(&Vf_sh[e]);
        Oacc[dg] = __builtin_amdgcn_mfma_f32_16x16x32_bf16(pf[kc], vf, Oacc[dg], 0, 0, 0);
      }
    }
  }

#pragma unroll
  for (int r = 0; r < 4; ++r) {
    float inv = 1.0f / l_run[r];
    int q = qblk * 64 + wv * 16 + lhi * 4 + r;
    float* orow = Op + (size_t)q * DDIM;
#pragma unroll
    for (int dg = 0; dg < 8; ++dg)
      orow[dg * 16 + l16] = Oacc[dg][r] * inv;
  }
}

extern "C" void kernel_launch(void* const* d_in, const int* in_sizes, int n_in,
                              void* d_out, int out_size, void* d_ws, size_t ws_size,
                              hipStream_t stream) {
  const float* Q = (const float*)d_in[0];
  const float* K = (const float*)d_in[1];
  const float* V = (const float*)d_in[2];
  float* O = (float*)d_out;

  const size_t n_elem = (size_t)NBH * SLEN * DDIM;   // 16,777,216
  const size_t need   = 1024 + n_elem * 2;           // ctrl + Vt bf16

  if (ws_size >= need) {
    int* ctrl    = (int*)d_ws;                       // 129 ints used
    ushort_t* Vt = (ushort_t*)((char*)d_ws + 1024);
    hipMemsetAsync(d_ws, 0, 1024, stream);
    fattn13_kernel<<<dim3(NITEMS), dim3(512), 0, stream>>>(Q, K, V, Vt, O, ctrl);
  } else {
    fattn_kernel<<<dim3(SLEN / 64, NBH), dim3(256), 0, stream>>>(Q, K, V, O);
  }
}

// Round 14
// 136.336 us; speedup vs baseline: 8.0975x; 8.0975x over previous
//
#include <hip/hip_runtime.h>

// Flash-attention forward, causal, B=4 H=16 S=2048 D=128, fp32 in/out.
// FINAL (= round 9, session best 136.5us): persistent LPT queue, 8-wave WGs,
// 32x32 MFMA swapped QK^T (S^T = K·Q^T so softmax rows are lane-local),
// in-register exp2-domain online softmax with defer-max (THR=11 log2),
// P^T fragments via v_cvt_pk_bf16_f32 + v_permlane32_swap_b32,
// O^T = V^T·P^T accumulation, K read fp32 and reg-staged->bf16 in-kernel
// (T14 async split), V pre-transposed to bf16 by a small prepass and staged
// via global_load_lds w=16 with pre-swizzled source (rule 21), 2-buf LDS.

#define SLEN 2048
#define DDIM 128
#define NBH  64
#define QB   256
#define KB   64
#define NITEMS 512

typedef __bf16 bf16x8 __attribute__((ext_vector_type(8)));
typedef float  f32x16 __attribute__((ext_vector_type(16)));
typedef float  f32x4  __attribute__((ext_vector_type(4)));
typedef unsigned uint32x4 __attribute__((ext_vector_type(4)));
typedef unsigned short ushort_t;
typedef ushort_t ushort8 __attribute__((ext_vector_type(8)));

__device__ inline ushort_t f2bf(float f) {
  union { float f; unsigned u; } v; v.f = f;
  unsigned u = v.u;
  u += 0x7FFFu + ((u >> 16) & 1u);   // RNE, finite inputs only
  return (ushort_t)(u >> 16);
}

__device__ inline unsigned cvtpk_bf16(float lo, float hi) {
  unsigned r;
  asm("v_cvt_pk_bf16_f32 %0, %1, %2" : "=v"(r) : "v"(lo), "v"(hi));
  return r;
}

__device__ inline float exp2_fast(float x) {
  float r;
  asm("v_exp_f32 %0, %1" : "=v"(r) : "v"(x));
  return r;
}

// ------------- pre-pass: V [bh][s][d] fp32 -> Vt [bh][d][s] bf16 + cnt=0 -----
__global__ __launch_bounds__(256) void prepass_kernel(
    const float* __restrict__ V, ushort_t* __restrict__ Vt,
    int* __restrict__ cnt) {
  __shared__ float t[64][33];
  if (blockIdx.x == 0 && threadIdx.x == 0) *cnt = 0;
  const int vb = (int)blockIdx.x;            // 8192 blocks
  const int bh = vb >> 7;
  const int d0 = ((vb >> 5) & 3) * 32;
  const int s0 = (vb & 31) * 64;
  const int tx = threadIdx.x & 31;
  const int ty = threadIdx.x >> 5;
  const float* src = V + ((size_t)bh * SLEN + s0) * DDIM + d0;
#pragma unroll
  for (int j = 0; j < 8; ++j) {
    int sl = ty + j * 8;
    t[sl][tx] = src[(size_t)sl * DDIM + tx];
  }
  __syncthreads();
  ushort_t* dst = Vt + ((size_t)bh * DDIM + d0) * SLEN + s0;
#pragma unroll
  for (int j = 0; j < 4; ++j) {
    int dl = ty + j * 8;
    unsigned lo = f2bf(t[tx * 2][dl]);
    unsigned hi = f2bf(t[tx * 2 + 1][dl]);
    *reinterpret_cast<unsigned*>(&dst[(size_t)dl * SLEN + tx * 2]) =
        lo | (hi << 16);
  }
}

// ---------------- main kernel: persistent, 8 waves, 32x32 MFMA ---------------
__global__ __launch_bounds__(512, 2) void fattn9_kernel(
    const float* __restrict__ Q, const float* __restrict__ Kf32,
    const ushort_t* __restrict__ Vt, float* __restrict__ Out,
    int* __restrict__ cnt) {
  __shared__ ushort_t K_sh[2][KB * DDIM];   // [buf][k][d]  16KB each
  __shared__ ushort_t V_sh[2][DDIM * KB];   // [buf][d][k]  16KB each
  __shared__ int item_sh;

  const int tid  = threadIdx.x;
  const int lane = tid & 63;
  const int wv   = tid >> 6;         // 0..7
  const int l31  = lane & 31;
  const int hi   = lane >> 5;        // 0/1

  // 1/sqrt(128) * log2(e): softmax runs in exp2 domain
  const float qscale = 0.12751744f;
  const float THR = 11.0f;           // defer-max threshold (log2 units)

  // K staging registers (2 chunks of 8 floats each), static-indexed
  float4 kr0a, kr0b, kr1a, kr1b;
  const int kch0 = tid;              // chunk ids: j*512 + tid
  const int kch1 = 512 + tid;
  const int krow0 = kch0 >> 4, kp0 = kch0 & 15;
  const int krow1 = kch1 >> 4, kp1 = kch1 & 15;
  const int kgc0 = kp0 ^ (krow0 & 7);          // global chunk (pre-swizzle)
  const int kgc1 = kp1 ^ (krow1 & 7);

  while (true) {
    if (tid == 0) item_sh = atomicAdd(cnt, 1);
    __syncthreads();
    const int item = item_sh;
    if (item >= NITEMS) break;

    const int qblk = 7 - (item >> 6);   // heavy-first (LPT)
    const int bh   = item & 63;

    const float*    Qp = Q    + (size_t)bh * SLEN * DDIM;
    const float*    Kp = Kf32 + (size_t)bh * SLEN * DDIM;
    const ushort_t* Vp = Vt   + (size_t)bh * DDIM * SLEN;
    float*          Op = Out  + (size_t)bh * SLEN * DDIM;

    const int q0w = qblk * QB + wv * 32;   // wave's first q row
    const int qg  = q0w + l31;             // this lane's q row

    // ---- Q fragments: B-operand of S^T = K·Q^T ----
    bf16x8 qf[8];
    {
      const float* qr = Qp + (size_t)qg * DDIM;
#pragma unroll
      for (int ds = 0; ds < 8; ++ds) {
        int d0 = ds * 16 + hi * 8;
        float4 x = *reinterpret_cast<const float4*>(qr + d0);
        float4 y = *reinterpret_cast<const float4*>(qr + d0 + 4);
        ushort8 uu;
        uu[0] = f2bf(x.x * qscale); uu[1] = f2bf(x.y * qscale);
        uu[2] = f2bf(x.z * qscale); uu[3] = f2bf(x.w * qscale);
        uu[4] = f2bf(y.x * qscale); uu[5] = f2bf(y.y * qscale);
        uu[6] = f2bf(y.z * qscale); uu[7] = f2bf(y.w * qscale);
        qf[ds] = __builtin_bit_cast(bf16x8, uu);
      }
    }

    f32x16 Oacc[4];
#pragma unroll
    for (int dt = 0; dt < 4; ++dt)
#pragma unroll
      for (int r = 0; r < 16; ++r) Oacc[dt][r] = 0.f;
    float m_run = -3.0e38f, l_run = 0.f;

    const int last_kb       = qblk * 4 + 3;
    const int last_kb_wave  = (q0w + 31) >> 6;

    // ---- K load (fp32 -> regs), pre-swizzled source ----
    auto kload = [&](int kb) {
      const float* ksrc = Kp + (size_t)kb * KB * DDIM;
      const float* g0 = ksrc + krow0 * DDIM + kgc0 * 8;
      const float* g1 = ksrc + krow1 * DDIM + kgc1 * 8;
      kr0a = *reinterpret_cast<const float4*>(g0);
      kr0b = *reinterpret_cast<const float4*>(g0 + 4);
      kr1a = *reinterpret_cast<const float4*>(g1);
      kr1b = *reinterpret_cast<const float4*>(g1 + 4);
    };
    // ---- K write (cvt_pk + ds_write_b128 to linear position) ----
    auto kwrite = [&](int buf) {
      uint32x4 w0, w1;
      w0.x = cvtpk_bf16(kr0a.x, kr0a.y); w0.y = cvtpk_bf16(kr0a.z, kr0a.w);
      w0.z = cvtpk_bf16(kr0b.x, kr0b.y); w0.w = cvtpk_bf16(kr0b.z, kr0b.w);
      w1.x = cvtpk_bf16(kr1a.x, kr1a.y); w1.y = cvtpk_bf16(kr1a.z, kr1a.w);
      w1.z = cvtpk_bf16(kr1b.x, kr1b.y); w1.w = cvtpk_bf16(kr1b.z, kr1b.w);
      *reinterpret_cast<uint32x4*>(&K_sh[buf][krow0 * DDIM + kp0 * 8]) = w0;
      *reinterpret_cast<uint32x4*>(&K_sh[buf][krow1 * DDIM + kp1 * 8]) = w1;
    };
    // ---- V stage via global_load_lds (bf16, pre-swizzled source) ----
    auto vstage = [&](int buf, int kb) {
      const ushort_t* vsrc = Vp + (size_t)kb * KB;
#pragma unroll
      for (int j = 0; j < 2; ++j) {
        int chunk = wv * 128 + j * 64 + lane;
        int row = chunk >> 3, c = chunk & 7;
        const ushort_t* g = vsrc + (size_t)row * SLEN + ((c ^ (row & 7)) << 3);
        ushort_t* l = &V_sh[buf][(wv * 128 + j * 64) * 8];
        __builtin_amdgcn_global_load_lds(
            (const __attribute__((address_space(1))) unsigned*)g,
            (__attribute__((address_space(3))) unsigned*)l, 16, 0, 0);
      }
    };

    // ---- prologue: stage tile 0 ----
    kload(0);
    vstage(0, 0);
    kwrite(0);
    __syncthreads();

    for (int kb = 0; kb <= last_kb; ++kb) {
      const int buf = kb & 1;
      if (kb < last_kb) {              // issue next tile's loads early (T14)
        kload(kb + 1);
        vstage(buf ^ 1, kb + 1);
      }

      if (kb <= last_kb_wave) {
        // ---- S^T = K·Q^T ----
        f32x16 sac[2];
#pragma unroll
        for (int mt = 0; mt < 2; ++mt) {
          f32x16 a;
#pragma unroll
          for (int r = 0; r < 16; ++r) a[r] = 0.f;
          int row = mt * 32 + l31;
          int sw = row & 7;
          __builtin_amdgcn_s_setprio(1);
#pragma unroll
          for (int ds = 0; ds < 8; ++ds) {
            int c = ds * 2 + hi;
            bf16x8 kf = *reinterpret_cast<const bf16x8*>(
                &K_sh[buf][row * DDIM + ((c ^ sw) << 3)]);
            a = __builtin_amdgcn_mfma_f32_32x32x16_bf16(kf, qf[ds], a, 0, 0, 0);
          }
          __builtin_amdgcn_s_setprio(0);
          sac[mt] = a;
        }

        // ---- causal mask (diagonal-crossing tiles only) ----
        if (kb * 64 + 63 > q0w) {
#pragma unroll
          for (int mt = 0; mt < 2; ++mt) {
            int kbase = kb * 64 + mt * 32 + 4 * hi;
#pragma unroll
            for (int r = 0; r < 16; ++r) {
              int krow = (r & 3) + 8 * (r >> 2);
              if (kbase + krow > qg) sac[mt][r] = -3.0e38f;
            }
          }
        }

        // ---- tile max: 4-way partial chains ----
        float p0 = sac[0][0], p1 = sac[0][1], p2 = sac[0][2], p3 = sac[0][3];
#pragma unroll
        for (int r = 4; r < 16; r += 4) {
          p0 = fmaxf(p0, sac[0][r + 0]); p1 = fmaxf(p1, sac[0][r + 1]);
          p2 = fmaxf(p2, sac[0][r + 2]); p3 = fmaxf(p3, sac[0][r + 3]);
        }
#pragma unroll
        for (int r = 0; r < 16; r += 4) {
          p0 = fmaxf(p0, sac[1][r + 0]); p1 = fmaxf(p1, sac[1][r + 1]);
          p2 = fmaxf(p2, sac[1][r + 2]); p3 = fmaxf(p3, sac[1][r + 3]);
        }
        float tm = fmaxf(fmaxf(p0, p1), fmaxf(p2, p3));
        tm = fmaxf(tm, __shfl_xor(tm, 32));

        // ---- defer-max ----
        if (!__all(tm - m_run <= THR)) {
          float mnew  = fmaxf(m_run, tm);
          float alpha = exp2_fast(m_run - mnew);
          m_run = mnew;
          l_run *= alpha;
#pragma unroll
          for (int dt = 0; dt < 4; ++dt)
#pragma unroll
            for (int r = 0; r < 16; ++r) Oacc[dt][r] *= alpha;
        }

        // ---- P = exp2(S - m), 4-way partial sums ----
        float s0 = 0.f, s1 = 0.f, s2 = 0.f, s3 = 0.f;
#pragma unroll
        for (int mt = 0; mt < 2; ++mt)
#pragma unroll
          for (int r = 0; r < 16; r += 4) {
            float e0 = exp2_fast(sac[mt][r + 0] - m_run);
            float e1 = exp2_fast(sac[mt][r + 1] - m_run);
            float e2 = exp2_fast(sac[mt][r + 2] - m_run);
            float e3 = exp2_fast(sac[mt][r + 3] - m_run);
            sac[mt][r + 0] = e0; sac[mt][r + 1] = e1;
            sac[mt][r + 2] = e2; sac[mt][r + 3] = e3;
            s0 += e0; s1 += e1; s2 += e2; s3 += e3;
          }
        float rs = (s0 + s1) + (s2 + s3);
        rs += __shfl_xor(rs, 32);
        l_run += rs;

        // ---- P^T fragments: cvt_pk + permlane32_swap ----
        uint32x4 pw[4];
#pragma unroll
        for (int ks = 0; ks < 4; ++ks) {
          const int mt = ks >> 1;
          const int hb = 8 * (ks & 1);
          unsigned X  = cvtpk_bf16(sac[mt][hb + 0], sac[mt][hb + 1]);
          unsigned X2 = cvtpk_bf16(sac[mt][hb + 2], sac[mt][hb + 3]);
          unsigned Y  = cvtpk_bf16(sac[mt][hb + 4], sac[mt][hb + 5]);
          unsigned Y2 = cvtpk_bf16(sac[mt][hb + 6], sac[mt][hb + 7]);
          asm("v_permlane32_swap_b32 %0, %1" : "+v"(X),  "+v"(Y));
          asm("v_permlane32_swap_b32 %0, %1" : "+v"(X2), "+v"(Y2));
          uint32x4 f; f.x = X; f.y = X2; f.z = Y; f.w = Y2;
          pw[ks] = f;
        }

        // ---- O^T += V^T · P^T ----
#pragma unroll
        for (int dt = 0; dt < 4; ++dt) {
          int row = dt * 32 + l31;
          int sw = row & 7;
          __builtin_amdgcn_s_setprio(1);
#pragma unroll
          for (int ks = 0; ks < 4; ++ks) {
            int c = ks * 2 + hi;
            bf16x8 vf = *reinterpret_cast<const bf16x8*>(
                &V_sh[buf][row * 64 + ((c ^ sw) << 3)]);
            Oacc[dt] = __builtin_amdgcn_mfma_f32_32x32x16_bf16(
                vf, __builtin_bit_cast(bf16x8, pw[ks]), Oacc[dt], 0, 0, 0);
          }
          __builtin_amdgcn_s_setprio(0);
        }
      }

      if (kb < last_kb) kwrite(buf ^ 1);   // convert+publish next K tile
      __syncthreads();                     // tile kb+1 resident for all waves
    }

    // ---- epilogue: O[q][d] = O^T normalized, float4 stores ----
    {
      float invl = 1.0f / l_run;
      float* orow = Op + (size_t)qg * DDIM;
#pragma unroll
      for (int dt = 0; dt < 4; ++dt)
#pragma unroll
        for (int rq = 0; rq < 4; ++rq) {
          float4 o;
          o.x = Oacc[dt][rq * 4 + 0] * invl;
          o.y = Oacc[dt][rq * 4 + 1] * invl;
          o.z = Oacc[dt][rq * 4 + 2] * invl;
          o.w = Oacc[dt][rq * 4 + 3] * invl;
          int d = dt * 32 + 8 * rq + 4 * hi;
          *reinterpret_cast<float4*>(orow + d) = o;
        }
    }
    __syncthreads();   // protect item_sh + LDS reuse across items
  }
}

// ---------------- fallback (fp32-direct kernel, used if ws too small) --------
__global__ __launch_bounds__(256) void fattn_kernel(
    const float* __restrict__ Q, const float* __restrict__ K,
    const float* __restrict__ V, float* __restrict__ Out) {
  __shared__ ushort_t Kf_sh[64 * 128];
  __shared__ ushort_t Vf_sh[128 * 64];
  __shared__ ushort_t P_sh[4][16 * 64];

  const int tid  = threadIdx.x;
  const int lane = tid & 63;
  const int wv   = tid >> 6;
  const int l16  = lane & 15;
  const int lhi  = lane >> 4;
  const int qblk = blockIdx.x;
  const int bh   = blockIdx.y;
  const float scale = 0.08838834764831845f;

  const size_t base = (size_t)bh * SLEN * DDIM;
  const float* Qp = Q + base;
  const float* Kp = K + base;
  const float* Vp = V + base;
  float*       Op = Out + base;

  bf16x8 qf[4];
  {
    const int qrow = qblk * 64 + wv * 16 + l16;
    const float* qr = Qp + (size_t)qrow * DDIM;
#pragma unroll
    for (int dc = 0; dc < 4; ++dc) {
      int d0 = dc * 32 + lhi * 8;
      float4 x = *reinterpret_cast<const float4*>(qr + d0);
      float4 y = *reinterpret_cast<const float4*>(qr + d0 + 4);
      ushort8 uu;
      uu[0] = f2bf(x.x * scale); uu[1] = f2bf(x.y * scale);
      uu[2] = f2bf(x.z * scale); uu[3] = f2bf(x.w * scale);
      uu[4] = f2bf(y.x * scale); uu[5] = f2bf(y.y * scale);
      uu[6] = f2bf(y.z * scale); uu[7] = f2bf(y.w * scale);
      qf[dc] = __builtin_bit_cast(bf16x8, uu);
    }
  }

  f32x4 Oacc[8];
#pragma unroll
  for (int i = 0; i < 8; ++i) Oacc[i] = (f32x4){0.f, 0.f, 0.f, 0.f};
  float m_run[4], l_run[4];
#pragma unroll
  for (int r = 0; r < 4; ++r) { m_run[r] = -3.0e38f; l_run[r] = 0.f; }

  for (int kb = 0; kb <= qblk; ++kb) {
    __syncthreads();
    {
      const float* src = Kp + (size_t)kb * 64 * DDIM;
#pragma unroll
      for (int it = 0; it < 8; ++it) {
        int idx4 = it * 256 + tid;
        int r  = idx4 >> 5;
        int c4 = idx4 & 31;
        float4 x = *reinterpret_cast<const float4*>(src + r * DDIM + c4 * 4);
        unsigned lo = ((unsigned)f2bf(x.y) << 16) | f2bf(x.x);
        unsigned hh = ((unsigned)f2bf(x.w) << 16) | f2bf(x.z);
        int e = (r * 128 + c4 * 4) ^ ((r & 7) << 3);
        *reinterpret_cast<uint2*>(&Kf_sh[e]) = make_uint2(lo, hh);
      }
      const float* vs = Vp + (size_t)kb * 64 * DDIM;
#pragma unroll
      for (int it = 0; it < 8; ++it) {
        int idx4 = it * 256 + tid;
        int r  = idx4 >> 5;
        int c4 = idx4 & 31;
        float4 x = *reinterpret_cast<const float4*>(vs + r * DDIM + c4 * 4);
        int c0 = c4 * 4;
        float vals[4] = {x.x, x.y, x.z, x.w};
#pragma unroll
        for (int j = 0; j < 4; ++j) {
          int d = c0 + j;
          Vf_sh[(d * 64 + r) ^ ((d & 7) << 3)] = f2bf(vals[j]);
        }
      }
    }
    __syncthreads();

    f32x4 sacc[4];
#pragma unroll
    for (int g = 0; g < 4; ++g) {
      f32x4 acc = (f32x4){0.f, 0.f, 0.f, 0.f};
#pragma unroll
      for (int dc = 0; dc < 4; ++dc) {
        int row = g * 16 + l16;
        int e = (row * 128 + dc * 32 + lhi * 8) ^ ((row & 7) << 3);
        bf16x8 kf = *reinterpret_cast<const bf16x8*>(&Kf_sh[e]);
        acc = __builtin_amdgcn_mfma_f32_16x16x32_bf16(qf[dc], kf, acc, 0, 0, 0);
      }
      sacc[g] = acc;
    }

    if (kb == qblk) {
      int q0 = lhi * 4;
#pragma unroll
      for (int g = 0; g < 4; ++g) {
        int kcol = g * 16 + l16;
#pragma unroll
        for (int r = 0; r < 4; ++r) {
          if (kcol > wv * 16 + q0 + r) sacc[g][r] = -3.0e38f;
        }
      }
    }

    float tmax[4];
#pragma unroll
    for (int r = 0; r < 4; ++r)
      tmax[r] = fmaxf(fmaxf(sacc[0][r], sacc[1][r]),
                      fmaxf(sacc[2][r], sacc[3][r]));
#pragma unroll
    for (int x = 1; x < 16; x <<= 1) {
#pragma unroll
      for (int r = 0; r < 4; ++r)
        tmax[r] = fmaxf(tmax[r], __shfl_xor(tmax[r], x));
    }

    float alpha[4], mnew[4];
#pragma unroll
    for (int r = 0; r < 4; ++r) {
      mnew[r]  = fmaxf(m_run[r], tmax[r]);
      alpha[r] = __expf(m_run[r] - mnew[r]);
      m_run[r] = mnew[r];
    }

    float rsum[4] = {0.f, 0.f, 0.f, 0.f};
#pragma unroll
    for (int g = 0; g < 4; ++g) {
#pragma unroll
      for (int r = 0; r < 4; ++r) {
        float p = __expf(sacc[g][r] - mnew[r]);
        rsum[r] += p;
        int prow = lhi * 4 + r;
        P_sh[wv][(prow * 64 + g * 16 + l16) ^ ((prow & 7) << 3)] = f2bf(p);
      }
    }
#pragma unroll
    for (int x = 1; x < 16; x <<= 1) {
#pragma unroll
      for (int r = 0; r < 4; ++r) rsum[r] += __shfl_xor(rsum[r], x);
    }
#pragma unroll
    for (int r = 0; r < 4; ++r) l_run[r] = l_run[r] * alpha[r] + rsum[r];

#pragma unroll
    for (int dg = 0; dg < 8; ++dg)
#pragma unroll
      for (int r = 0; r < 4; ++r) Oacc[dg][r] *= alpha[r];

    bf16x8 pf[2];
#pragma unroll
    for (int kc = 0; kc < 2; ++kc) {
      int e = (l16 * 64 + kc * 32 + lhi * 8) ^ ((l16 & 7) << 3);
      pf[kc] = *reinterpret_cast<const bf16x8*>(&P_sh[wv][e]);
    }
#pragma unroll
    for (int dg = 0; dg < 8; ++dg) {
#pragma unroll
      for (int kc = 0; kc < 2; ++kc) {
        int row = dg * 16 + l16;
        int e = (row * 64 + kc * 32 + lhi * 8) ^ ((row & 7) << 3);
        bf16x8 vf = *reinterpret_cast<const bf16x8*>(&Vf_sh[e]);
        Oacc[dg] = __builtin_amdgcn_mfma_f32_16x16x32_bf16(pf[kc], vf, Oacc[dg], 0, 0, 0);
      }
    }
  }

#pragma unroll
  for (int r = 0; r < 4; ++r) {
    float inv = 1.0f / l_run[r];
    int q = qblk * 64 + wv * 16 + lhi * 4 + r;
    float* orow = Op + (size_t)q * DDIM;
#pragma unroll
    for (int dg = 0; dg < 8; ++dg)
      orow[dg * 16 + l16] = Oacc[dg][r] * inv;
  }
}

extern "C" void kernel_launch(void* const* d_in, const int* in_sizes, int n_in,
                              void* d_out, int out_size, void* d_ws, size_t ws_size,
                              hipStream_t stream) {
  const float* Q = (const float*)d_in[0];
  const float* K = (const float*)d_in[1];
  const float* V = (const float*)d_in[2];
  float* O = (float*)d_out;

  const size_t n_elem = (size_t)NBH * SLEN * DDIM;   // 16,777,216
  const size_t need   = n_elem * 2 + 64;             // Vt bf16 + counter

  if (ws_size >= need) {
    ushort_t* Vt = (ushort_t*)d_ws;
    int* cnt     = (int*)(Vt + n_elem);
    prepass_kernel<<<8192, 256, 0, stream>>>(V, Vt, cnt);
    fattn9_kernel<<<dim3(NITEMS), dim3(512), 0, stream>>>(Q, K, Vt, O, cnt);
  } else {
    fattn_kernel<<<dim3(SLEN / 64, NBH), dim3(256), 0, stream>>>(Q, K, V, O);
  }
}